// Round 1
// baseline (444.630 us; speedup 1.0000x reference)
//
#include <hip/hip_runtime.h>

#define BB 16
#define TT 512
#define DD 64
#define HH 128
#define SS 100
#define MSZ 20
#define NROW (BB*TT)      // 8192
#define FOURH 512

__device__ __forceinline__ float frcp(float x){ return __builtin_amdgcn_rcpf(x); }
__device__ __forceinline__ float sigmoidf_(float x){
    return frcp(1.0f + __expf(-x));
}
__device__ __forceinline__ float tanhf_(float x){
    float t = __expf(2.0f * x);
    return 1.0f - 2.0f * frcp(t + 1.0f);   // rcp(inf)=0 -> saturates to +/-1
}

// ---------------- kernel A: xw = inputs @ lstm_kernel + bias ----------------
__global__ __launch_bounds__(512) void k_xw(const float* __restrict__ inp,
        const float* __restrict__ Wk, const float* __restrict__ bias,
        float* __restrict__ xw){
    __shared__ float in_s[8 * DD];
    int tid = threadIdx.x;
    int r0 = blockIdx.x * 8;
    in_s[tid] = inp[(size_t)r0 * DD + tid];
    __syncthreads();
    int j = tid;
    float wreg[DD];
    #pragma unroll
    for (int d = 0; d < DD; ++d) wreg[d] = Wk[d * FOURH + j];
    float bv = bias[j];
    const float4* in4 = reinterpret_cast<const float4*>(in_s);
    #pragma unroll
    for (int r = 0; r < 8; ++r){
        float acc = bv;
        #pragma unroll
        for (int q = 0; q < DD/4; ++q){
            float4 iv = in4[r*(DD/4) + q];
            acc = fmaf(iv.x, wreg[4*q+0], acc);
            acc = fmaf(iv.y, wreg[4*q+1], acc);
            acc = fmaf(iv.z, wreg[4*q+2], acc);
            acc = fmaf(iv.w, wreg[4*q+3], acc);
        }
        xw[(size_t)(r0 + r) * FOURH + j] = acc;
    }
}

// ---------------- kernel B: LSTM scan, one block per batch element ----------
__global__ __launch_bounds__(1024) void k_scan(const float* __restrict__ xw,
        const float* __restrict__ Rk, float* __restrict__ ctrl){
    __shared__ float h_lds[HH];
    __shared__ float part[1024];
    int tid = threadIdx.x;
    int b = blockIdx.x;
    int j = tid & 511;
    int half = tid >> 9;
    float rk[64];
    #pragma unroll
    for (int k = 0; k < 64; ++k) rk[k] = Rk[(half*64 + k) * FOURH + j];
    if (tid < HH) h_lds[tid] = 0.0f;
    float c = 0.0f;
    float xp0 = 0.f, xp1 = 0.f, xp2 = 0.f, xp3 = 0.f;
    if (tid < HH){
        const float* xr = xw + (size_t)b * TT * FOURH;   // t = 0
        xp0 = xr[tid]; xp1 = xr[128 + tid]; xp2 = xr[256 + tid]; xp3 = xr[384 + tid];
    }
    __syncthreads();
    for (int t = 0; t < TT; ++t){
        float acc = 0.0f;
        const float4* h4 = reinterpret_cast<const float4*>(h_lds + half*64);
        #pragma unroll
        for (int q = 0; q < 16; ++q){
            float4 hv = h4[q];
            acc = fmaf(hv.x, rk[4*q+0], acc);
            acc = fmaf(hv.y, rk[4*q+1], acc);
            acc = fmaf(hv.z, rk[4*q+2], acc);
            acc = fmaf(hv.w, rk[4*q+3], acc);
        }
        part[tid] = acc;
        __syncthreads();
        if (tid < HH){
            int k = tid;
            float zi = part[k]       + part[512 + k] + xp0;
            float zf = part[128 + k] + part[640 + k] + xp1;
            float zg = part[256 + k] + part[768 + k] + xp2;
            float zo = part[384 + k] + part[896 + k] + xp3;
            float ig = sigmoidf_(zi);
            float fg = sigmoidf_(zf);
            float gg = tanhf_(zg);
            float og = sigmoidf_(zo);
            c = fg * c + ig * gg;
            float h = og * tanhf_(c);
            h_lds[k] = h;
            ctrl[((size_t)b * TT + t) * HH + k] = h;
            if (t + 1 < TT){
                const float* xr = xw + ((size_t)b * TT + t + 1) * FOURH;
                xp0 = xr[k]; xp1 = xr[128 + k]; xp2 = xr[256 + k]; xp3 = xr[384 + k];
            }
        }
        __syncthreads();
    }
}

// ---------------- kernel C: proj = ctrl @ [8 heads' W] + biases; also copies
// ctrl into out[:, 0:128] ----------------------------------------------------
__global__ __launch_bounds__(320) void k_proj(const float* __restrict__ ctrl,
        const float* __restrict__ rWk, const float* __restrict__ rbk,
        const float* __restrict__ wWk, const float* __restrict__ wbk,
        const float* __restrict__ wWe, const float* __restrict__ wbe,
        const float* __restrict__ wWa, const float* __restrict__ wba,
        float* __restrict__ proj, float* __restrict__ out){
    __shared__ float cs[16 * HH];
    int tid = threadIdx.x;
    int r0 = blockIdx.x * 16;
    for (int idx = tid; idx < 16 * HH; idx += 320){
        float v = ctrl[(size_t)r0 * HH + idx];
        cs[idx] = v;
        int r = idx >> 7, k = idx & 127;
        out[(size_t)(r0 + r) * 168 + k] = v;
    }
    __syncthreads();
    int j = tid % 160;
    int rh = tid / 160;
    int p = j / MSZ, m = j % MSZ;
    const float* Wp; const float* bp;
    switch (p){
        case 0:  Wp = rWk;            bp = rbk;        break;
        case 1:  Wp = rWk + HH*MSZ;   bp = rbk + MSZ;  break;
        case 2:  Wp = wWk;            bp = wbk;        break;
        case 3:  Wp = wWk + HH*MSZ;   bp = wbk + MSZ;  break;
        case 4:  Wp = wWe;            bp = wbe;        break;
        case 5:  Wp = wWe + HH*MSZ;   bp = wbe + MSZ;  break;
        case 6:  Wp = wWa;            bp = wba;        break;
        default: Wp = wWa + HH*MSZ;   bp = wba + MSZ;  break;
    }
    float wv[HH];
    #pragma unroll
    for (int k = 0; k < HH; ++k) wv[k] = Wp[k * MSZ + m];
    float bv = bp[m];
    #pragma unroll
    for (int r = 0; r < 8; ++r){
        int row = rh * 8 + r;
        float acc = bv;
        const float4* c4 = reinterpret_cast<const float4*>(cs + row * HH);
        #pragma unroll
        for (int q = 0; q < HH/4; ++q){
            float4 cv = c4[q];
            acc = fmaf(cv.x, wv[4*q+0], acc);
            acc = fmaf(cv.y, wv[4*q+1], acc);
            acc = fmaf(cv.z, wv[4*q+2], acc);
            acc = fmaf(cv.w, wv[4*q+3], acc);
        }
        proj[(size_t)(r0 + row) * 160 + j] = acc;
    }
}

// ---------------- kernel D: heads, one block per (b,t) ----------------------
__device__ __forceinline__ float blocksum128(float v, float* red){
    #pragma unroll
    for (int o = 1; o < 64; o <<= 1) v += __shfl_xor(v, o, 64);
    int tid = threadIdx.x;
    if ((tid & 63) == 0) red[tid >> 6] = v;
    __syncthreads();
    float s = red[0] + red[1];
    __syncthreads();
    return s;
}

__global__ __launch_bounds__(128) void k_heads(const float* __restrict__ proj,
        const float* __restrict__ memory, float* __restrict__ out,
        float* __restrict__ outmem){
    __shared__ float mem0[SS * MSZ];
    __shared__ float rn[SS];
    __shared__ float khat[4][MSZ];
    __shared__ float ea[4][MSZ];
    __shared__ float wrd[2][SS];
    __shared__ float red[2];
    __shared__ float pz[160];
    int tid = threadIdx.x;
    int bt = blockIdx.x;
    for (int idx = tid; idx < SS * MSZ; idx += 128) mem0[idx] = memory[idx];
    for (int idx = tid; idx < 160; idx += 128) pz[idx] = proj[(size_t)bt * 160 + idx];
    __syncthreads();
    if (tid < SS){
        float s2 = 0.0f;
        #pragma unroll
        for (int m = 0; m < MSZ; ++m){ float v = mem0[tid*MSZ + m]; s2 = fmaf(v, v, s2); }
        rn[tid] = rsqrtf(fmaxf(s2, 1e-12f));
    }
    {   // 4 key heads: softmax over 20 then l2-normalize; plus e/a heads
        int g = tid >> 5, lm = tid & 31;
        float z = (lm < MSZ) ? pz[g*MSZ + lm] : 0.0f;
        float e = (lm < MSZ) ? __expf(z) : 0.0f;
        float ssum = e;
        #pragma unroll
        for (int o = 1; o < 32; o <<= 1) ssum += __shfl_xor(ssum, o, 32);
        float kv = e / ssum;
        float qs = kv * kv;
        #pragma unroll
        for (int o = 1; o < 32; o <<= 1) qs += __shfl_xor(qs, o, 32);
        float kn = kv * rsqrtf(fmaxf(qs, 1e-12f));
        if (lm < MSZ) khat[g][lm] = kn;
        float z2 = (lm < MSZ) ? pz[80 + g*MSZ + lm] : 0.0f;
        float v2 = (g < 2) ? sigmoidf_(z2) : z2;
        if (lm < MSZ) ea[g][lm] = v2;
    }
    __syncthreads();
    bool act = tid < SS;
    int s = tid;
    float d0 = 0.f, d1 = 0.f, dw = 0.f;
    if (act){
        #pragma unroll
        for (int m = 0; m < MSZ; ++m){
            float mv = mem0[s*MSZ + m];
            d0 = fmaf(khat[0][m], mv, d0);
            d1 = fmaf(khat[1][m], mv, d1);
            dw = fmaf(khat[2][m], mv, dw);
        }
    }
    float rns = act ? rn[s] : 0.0f;
    float e0 = act ? __expf(-rns * d0) : 0.0f;
    float e1 = act ? __expf(-rns * d1) : 0.0f;
    float ew = act ? __expf(-rns * dw) : 0.0f;
    float sum0 = blocksum128(e0, red);
    float sum1 = blocksum128(e1, red);
    float sumw = blocksum128(ew, red);
    if (act){ wrd[0][s] = e0 / sum0; wrd[1][s] = e1 / sum1; }
    float w0 = ew / sumw;
    float m1[MSZ];
    float n1 = 0.f, dkw = 0.f;
    if (act){
        #pragma unroll
        for (int m = 0; m < MSZ; ++m){
            float mv = mem0[s*MSZ + m];
            float v = fmaf(-w0 * ea[0][m], mv, mv);   // (1 - w0*e0)*mem
            v = fmaf(w0, ea[2][m], v);                // + w0*a0
            m1[m] = v;
            n1 = fmaf(v, v, n1);
            dkw = fmaf(khat[3][m], v, dkw);
        }
    }
    float rn1 = rsqrtf(fmaxf(n1, 1e-12f));
    float e1w = act ? __expf(-rn1 * dkw) : 0.0f;
    float sum1w = blocksum128(e1w, red);
    float w1 = e1w / sum1w;
    if (act){
        float buf[MSZ];
        #pragma unroll
        for (int m = 0; m < MSZ; ++m){
            float v = m1[m];
            float v2 = fmaf(-w1 * ea[1][m], v, v);
            v2 = fmaf(w1, ea[3][m], v2);
            buf[m] = v2;
        }
        float4* dst = reinterpret_cast<float4*>(outmem + ((size_t)bt * SS + s) * MSZ);
        #pragma unroll
        for (int q = 0; q < MSZ/4; ++q)
            dst[q] = make_float4(buf[4*q], buf[4*q+1], buf[4*q+2], buf[4*q+3]);
    }
    __syncthreads();
    if (tid < 2 * MSZ){
        int hd = tid / MSZ, m = tid % MSZ;
        float acc = 0.0f;
        for (int s2 = 0; s2 < SS; ++s2)
            acc = fmaf(wrd[hd][s2], mem0[s2*MSZ + m], acc);
        out[(size_t)bt * 168 + 128 + hd*MSZ + m] = acc;
    }
}

extern "C" void kernel_launch(void* const* d_in, const int* in_sizes, int n_in,
                              void* d_out, int out_size, void* d_ws, size_t ws_size,
                              hipStream_t stream){
    const float* inputs = (const float*)d_in[0];
    const float* memory = (const float*)d_in[1];
    const float* Wk     = (const float*)d_in[2];
    const float* Rk     = (const float*)d_in[3];
    const float* bias   = (const float*)d_in[4];
    const float* rWk    = (const float*)d_in[5];
    const float* rbk    = (const float*)d_in[6];
    const float* wWk    = (const float*)d_in[7];
    const float* wbk    = (const float*)d_in[8];
    const float* wWe    = (const float*)d_in[9];
    const float* wbe    = (const float*)d_in[10];
    const float* wWa    = (const float*)d_in[11];
    const float* wba    = (const float*)d_in[12];

    float* out    = (float*)d_out;
    float* outmem = out + (size_t)NROW * 168;
    // xw scratch aliases the (dead until k_heads) mem-output region: 4.19M of 16.38M floats
    float* xw   = outmem;
    float* ctrl = (float*)d_ws;
    float* proj = ctrl + (size_t)NROW * HH;

    k_xw  <<<NROW/8,  512, 0, stream>>>(inputs, Wk, bias, xw);
    k_scan<<<BB,     1024, 0, stream>>>(xw, Rk, ctrl);
    k_proj<<<NROW/16, 320, 0, stream>>>(ctrl, rWk, rbk, wWk, wbk, wWe, wbe, wWa, wba, proj, out);
    k_heads<<<NROW,   128, 0, stream>>>(proj, memory, out, outmem);
}